// Round 2
// baseline (297.241 us; speedup 1.0000x reference)
//
#include <hip/hip_runtime.h>

#define Bd 16
#define Cd 512
#define Hd 64
#define Wd 64
#define HWd (Hd * Wd)
#define NCLS 5
#define BETA 2.0f
#define EPS2 (0.001f * 0.001f)

// channel-chunking: each block reduces CH channels for 1024 pixels.
// CH=16 -> grid 2048 blocks -> 8 blocks/CU, 32 waves/CU at VGPR<=64.
constexpr int CH = 16;
constexpr int NCCHUNK = Cd / CH;      // 32
constexpr int PIX_PER_BLOCK = 1024;   // 256 threads * 4 pixels (float4)
constexpr int KPART = 4 * NCCHUNK;    // 128 partial sums per (cls,b) bin

// mode 1 (partials): contention-free — each block stores its 5 LDS-reduced
//   sums at a unique slot. sumP: [NCLS][Bd][KPART] (40KB), cntP: [NCLS][Bd][4].
// mode 0 (atomic fallback, needs only 640B ws): global atomicAdd into
//   segsum[80]/segcnt[80] — the proven baseline epilogue.
// grid = (HW/1024, B, NCCHUNK), block = 256
__global__ __launch_bounds__(256, 8) void seg_partial_kernel(
    const float* __restrict__ rec, const float* __restrict__ aln,
    const int* __restrict__ mask,
    float* __restrict__ sumP, float* __restrict__ cntP, int mode)
{
    __shared__ float binS[NCLS];
    __shared__ float binC[NCLS];
    const int tid = threadIdx.x;
    if (tid < NCLS) { binS[tid] = 0.0f; binC[tid] = 0.0f; }
    __syncthreads();

    const int b   = blockIdx.y;
    const int hw0 = blockIdx.x * PIX_PER_BLOCK + tid * 4;
    const int c0  = blockIdx.z * CH;

    const size_t base = (size_t)(b * Cd + c0) * HWd + hw0;
    const float4* __restrict__ rv = (const float4*)(rec + base);
    const float4* __restrict__ av = (const float4*)(aln + base);
    constexpr int CSTRIDE = HWd / 4;   // float4 stride between channels

    // independent mask load (L2-resident, shared by all c-chunks)
    const int4 m = *(const int4*)(mask + b * HWd + hw0);

    float4 acc = make_float4(0.f, 0.f, 0.f, 0.f);
    // manual 4-channel unroll: 8 dwordx4 loads issued before any use.
#pragma unroll
    for (int cb = 0; cb < CH; cb += 4) {
        const float4* r4 = rv + (size_t)cb * CSTRIDE;
        const float4* a4 = av + (size_t)cb * CSTRIDE;
        float4 r0 = r4[0 * CSTRIDE];
        float4 r1 = r4[1 * CSTRIDE];
        float4 r2 = r4[2 * CSTRIDE];
        float4 r3 = r4[3 * CSTRIDE];
        float4 a0 = a4[0 * CSTRIDE];
        float4 a1 = a4[1 * CSTRIDE];
        float4 a2 = a4[2 * CSTRIDE];
        float4 a3 = a4[3 * CSTRIDE];

        float d;
        d = r0.x - a0.x; acc.x += d * d;
        d = r0.y - a0.y; acc.y += d * d;
        d = r0.z - a0.z; acc.z += d * d;
        d = r0.w - a0.w; acc.w += d * d;
        d = r1.x - a1.x; acc.x += d * d;
        d = r1.y - a1.y; acc.y += d * d;
        d = r1.z - a1.z; acc.z += d * d;
        d = r1.w - a1.w; acc.w += d * d;
        d = r2.x - a2.x; acc.x += d * d;
        d = r2.y - a2.y; acc.y += d * d;
        d = r2.z - a2.z; acc.z += d * d;
        d = r2.w - a2.w; acc.w += d * d;
        d = r3.x - a3.x; acc.x += d * d;
        d = r3.y - a3.y; acc.y += d * d;
        d = r3.z - a3.z; acc.z += d * d;
        d = r3.w - a3.w; acc.w += d * d;
    }

    const float scale = 1.0f / (float)Cd;   // channel mean
    atomicAdd(&binS[m.x], acc.x * scale);   // LDS atomics (5 addrs, per-block)
    atomicAdd(&binS[m.y], acc.y * scale);
    atomicAdd(&binS[m.z], acc.z * scale);
    atomicAdd(&binS[m.w], acc.w * scale);
    if (blockIdx.z == 0) {
        atomicAdd(&binC[m.x], 1.0f);
        atomicAdd(&binC[m.y], 1.0f);
        atomicAdd(&binC[m.z], 1.0f);
        atomicAdd(&binC[m.w], 1.0f);
    }
    __syncthreads();
    if (tid < NCLS) {
        if (mode) {
            // contention-free: plain stores to block-unique slots
            const int kb = blockIdx.x + 4 * blockIdx.z;          // 0..127
            sumP[(tid * Bd + b) * KPART + kb] = binS[tid];
            if (blockIdx.z == 0)
                cntP[(tid * Bd + b) * 4 + blockIdx.x] = binC[tid];
        } else {
            // baseline: global atomics into the 80 final bins
            atomicAdd(&sumP[b * NCLS + tid], binS[tid]);
            if (blockIdx.z == 0) atomicAdd(&cntP[b * NCLS + tid], binC[tid]);
        }
    }
}

// Kernel 2: (mode 1) reduce 80 bins x 128 partials, then the scalar epilogue.
//           (mode 0) bins already final; just the scalar epilogue.
// One block of 256 threads (4 waves; each wave owns bins w, w+4, ...).
__global__ __launch_bounds__(256) void finalize_kernel(
    const float* __restrict__ sumP, const float* __restrict__ cntP,
    float* __restrict__ out, int mode)
{
    const int t    = threadIdx.x;
    const int lane = t & 63;
    const int w    = t >> 6;

    __shared__ float segS[Bd * NCLS];
    __shared__ float segC[Bd * NCLS];
    __shared__ float red[256];

    if (mode) {
        // phase 1: tree-reduce the per-block partials (coalesced reads)
        for (int bin = w; bin < Bd * NCLS; bin += 4) {
            float a = sumP[bin * KPART + lane] + sumP[bin * KPART + 64 + lane];
#pragma unroll
            for (int off = 32; off > 0; off >>= 1) a += __shfl_down(a, off);
            float c = (lane < 4) ? cntP[bin * 4 + lane] : 0.0f;
            c += __shfl_down(c, 2);
            c += __shfl_down(c, 1);
            if (lane == 0) { segS[bin] = a; segC[bin] = c; }
        }
    } else {
        if (t < Bd * NCLS) {
            // mode 0: sumP/cntP are segsum[80]/segcnt[80] ([b][cls] layout)
            segS[((t % NCLS) * Bd) + (t / NCLS)] = sumP[t];
            segC[((t % NCLS) * Bd) + (t / NCLS)] = cntP[t];
        }
    }
    __syncthreads();

    // phase 2: wmax over the 80 segment averages
    float s = 0.0f, cnt = 0.0f, avg = 0.0f;
    if (t < Bd * NCLS) {
        s = segS[t];
        cnt = segC[t];
        avg = s / fmaxf(cnt, 1.0f);   // empty segments -> 0 (contribute nothing)
    }
    red[t] = avg;
    __syncthreads();
#pragma unroll
    for (int off = 128; off > 0; off >>= 1) {
        if (t < off) red[t] = fmaxf(red[t], red[t + off]);
        __syncthreads();
    }
    const float wmax = red[0];
    __syncthreads();   // everyone has wmax before red[] is reused

    float wgt = (wmax > 0.0f) ? (avg / (wmax + EPS2)) : (avg + EPS2);
    wgt = fminf(fmaxf(wgt, 0.0f), 1.0f);

    red[t] = s * (wgt * BETA + 1.0f);
    __syncthreads();
#pragma unroll
    for (int off = 128; off > 0; off >>= 1) {
        if (t < off) red[t] += red[t + off];
        __syncthreads();
    }
    if (t == 0) out[0] = red[0] / (float)(Bd * HWd);
}

extern "C" void kernel_launch(void* const* d_in, const int* in_sizes, int n_in,
                              void* d_out, int out_size, void* d_ws, size_t ws_size,
                              hipStream_t stream) {
    const float* rec  = (const float*)d_in[0];
    const float* aln  = (const float*)d_in[1];
    const int*   mask = (const int*)d_in[2];
    float* out = (float*)d_out;

    // partials table: sumP [5][16][128] = 40KB + cntP [5][16][4] = 1.25KB
    const size_t needP = (size_t)(NCLS * Bd * KPART + NCLS * Bd * 4) * sizeof(float);
    const int mode = (ws_size >= needP) ? 1 : 0;

    float* sumP = (float*)d_ws;
    float* cntP;
    if (mode) {
        cntP = sumP + NCLS * Bd * KPART;
        // every slot is written by kernel 1 -> no memset needed
    } else {
        cntP = sumP + Bd * NCLS;
        hipMemsetAsync(d_ws, 0, 2 * Bd * NCLS * sizeof(float), stream);
    }

    dim3 grid(HWd / PIX_PER_BLOCK, Bd, NCCHUNK);   // (4, 16, 32) = 2048 blocks
    seg_partial_kernel<<<grid, 256, 0, stream>>>(rec, aln, mask, sumP, cntP, mode);
    finalize_kernel<<<1, 256, 0, stream>>>(sumP, cntP, out, mode);
}

// Round 3
// 285.774 us; speedup vs baseline: 1.0401x; 1.0401x over previous
//
#include <hip/hip_runtime.h>

#define Bd 16
#define Cd 512
#define Hd 64
#define Wd 64
#define HWd (Hd * Wd)
#define NCLS 5
#define BETA 2.0f
#define EPS2 (0.001f * 0.001f)

// channel-chunking: each block reduces CH channels for 1024 pixels.
// CH=16 -> grid 2048 blocks.
// __launch_bounds__(256,4): VGPR cap 128 so the 16-float4 in-flight batch
// (64 data VGPRs) actually materializes. At (256,8)/VGPR=32 the compiler
// spilled 16 B/thread (WRITE_SIZE 8.4 MB) and serialized the loads.
constexpr int CH = 16;
constexpr int NCCHUNK = Cd / CH;      // 32
constexpr int PIX_PER_BLOCK = 1024;   // 256 threads * 4 pixels (float4)

// Kernel 1: per-pixel channel-MSE partial sums -> per-(batch,class) segment
// sums via LDS bins + one global atomic per (block,class).
// grid = (HW/1024, B, NCCHUNK), block = 256
__global__ __launch_bounds__(256, 4) void seg_partial_kernel(
    const float* __restrict__ rec, const float* __restrict__ aln,
    const int* __restrict__ mask,
    float* __restrict__ segsum, float* __restrict__ segcnt)
{
    __shared__ float binS[NCLS];
    __shared__ float binC[NCLS];
    const int tid = threadIdx.x;
    if (tid < NCLS) { binS[tid] = 0.0f; binC[tid] = 0.0f; }
    __syncthreads();

    const int b   = blockIdx.y;
    const int hw0 = blockIdx.x * PIX_PER_BLOCK + tid * 4;
    const int c0  = blockIdx.z * CH;

    const size_t base = (size_t)(b * Cd + c0) * HWd + hw0;
    const float4* __restrict__ rv = (const float4*)(rec + base);
    const float4* __restrict__ av = (const float4*)(aln + base);
    constexpr int CSTRIDE = HWd / 4;   // float4 stride between channels

    // independent mask load (L2-resident, shared by all c-chunks)
    const int4 m = *(const int4*)(mask + b * HWd + hw0);

    float4 acc = make_float4(0.f, 0.f, 0.f, 0.f);

    // two 8-channel batches; each batch issues 16 dwordx4 loads (64 VGPRs of
    // data) before any use -> 16 KB outstanding per wave, no spill.
#pragma unroll
    for (int batch = 0; batch < 2; ++batch) {
        const float4* r4 = rv + (size_t)(batch * 8) * CSTRIDE;
        const float4* a4 = av + (size_t)(batch * 8) * CSTRIDE;
        float4 R[8], A[8];
#pragma unroll
        for (int j = 0; j < 8; ++j) R[j] = r4[(size_t)j * CSTRIDE];
#pragma unroll
        for (int j = 0; j < 8; ++j) A[j] = a4[(size_t)j * CSTRIDE];
#pragma unroll
        for (int j = 0; j < 8; ++j) {
            float d;
            d = R[j].x - A[j].x; acc.x += d * d;
            d = R[j].y - A[j].y; acc.y += d * d;
            d = R[j].z - A[j].z; acc.z += d * d;
            d = R[j].w - A[j].w; acc.w += d * d;
        }
    }

    const float scale = 1.0f / (float)Cd;   // channel mean
    atomicAdd(&binS[m.x], acc.x * scale);   // LDS atomics (5 addrs, per-block)
    atomicAdd(&binS[m.y], acc.y * scale);
    atomicAdd(&binS[m.z], acc.z * scale);
    atomicAdd(&binS[m.w], acc.w * scale);
    if (blockIdx.z == 0) {
        atomicAdd(&binC[m.x], 1.0f);
        atomicAdd(&binC[m.y], 1.0f);
        atomicAdd(&binC[m.z], 1.0f);
        atomicAdd(&binC[m.w], 1.0f);
    }
    __syncthreads();
    // global atomics into the 80 final bins (round-0 epilogue: measured
    // faster than the contention-free partials table, and simpler)
    if (tid < NCLS) {
        atomicAdd(&segsum[b * NCLS + tid], binS[tid]);
        if (blockIdx.z == 0) atomicAdd(&segcnt[b * NCLS + tid], binC[tid]);
    }
}

// Kernel 2: 80 segments -> scalar. One block of 128 threads.
__global__ __launch_bounds__(128) void finalize_kernel(
    const float* __restrict__ segsum, const float* __restrict__ segcnt,
    float* __restrict__ out)
{
    __shared__ float sMax[128];
    __shared__ float sSum[128];
    const int t = threadIdx.x;

    float s = 0.0f, cnt = 0.0f;
    if (t < Bd * NCLS) { s = segsum[t]; cnt = segcnt[t]; }
    const float avg = s / fmaxf(cnt, 1.0f);   // empty segments -> 0

    sMax[t] = avg;
    __syncthreads();
#pragma unroll
    for (int off = 64; off > 0; off >>= 1) {
        if (t < off) sMax[t] = fmaxf(sMax[t], sMax[t + off]);
        __syncthreads();
    }
    const float wmax = sMax[0];

    float w = (wmax > 0.0f) ? (avg / (wmax + EPS2)) : (avg + EPS2);
    w = fminf(fmaxf(w, 0.0f), 1.0f);

    sSum[t] = s * (w * BETA + 1.0f);
    __syncthreads();
#pragma unroll
    for (int off = 64; off > 0; off >>= 1) {
        if (t < off) sSum[t] += sSum[t + off];
        __syncthreads();
    }
    if (t == 0) out[0] = sSum[0] / (float)(Bd * HWd);
}

extern "C" void kernel_launch(void* const* d_in, const int* in_sizes, int n_in,
                              void* d_out, int out_size, void* d_ws, size_t ws_size,
                              hipStream_t stream) {
    const float* rec  = (const float*)d_in[0];
    const float* aln  = (const float*)d_in[1];
    const int*   mask = (const int*)d_in[2];
    float* out = (float*)d_out;

    float* segsum = (float*)d_ws;
    float* segcnt = segsum + Bd * NCLS;

    // zero the 2*80 accumulators (ws is re-poisoned to 0xAA before every launch)
    hipMemsetAsync(d_ws, 0, 2 * Bd * NCLS * sizeof(float), stream);

    dim3 grid(HWd / PIX_PER_BLOCK, Bd, NCCHUNK);   // (4, 16, 32) = 2048 blocks
    seg_partial_kernel<<<grid, 256, 0, stream>>>(rec, aln, mask, segsum, segcnt);
    finalize_kernel<<<1, 128, 0, stream>>>(segsum, segcnt, out);
}

// Round 5
// 267.938 us; speedup vs baseline: 1.1094x; 1.0666x over previous
//
#include <hip/hip_runtime.h>

#define Bd 16
#define Cd 512
#define Hd 64
#define Wd 64
#define HWd (Hd * Wd)
#define NCLS 5
#define BETA 2.0f
#define EPS2 (0.001f * 0.001f)

// native 4-float vector: __builtin_nontemporal_load requires a scalar/native
// vector pointee (HIP's float4 is a struct and is rejected).
typedef float f4 __attribute__((ext_vector_type(4)));

// CH=8 -> grid (4,16,64) = 4096 blocks -> 16 blocks/CU available, 8 co-resident
// at (256,8). Surplus blocks keep CUs fed through dispatch ramp/tail.
// Loads are nontemporal (streaming): working set (268MB) > L3 (256MB), so L3
// hits ~50% but the L3-hit path appears to ceiling ~2.45 TB/s; HBM has 6.5 TB/s
// of idle headroom.
constexpr int CH = 8;
constexpr int NCCHUNK = Cd / CH;      // 64
constexpr int PIX_PER_BLOCK = 1024;   // 256 threads * 4 pixels (float4)

// Kernel 1: per-pixel channel-MSE partial sums -> per-(batch,class) segment
// sums via LDS bins + one global atomic per (block,class).
// grid = (HW/1024, B, NCCHUNK), block = 256
__global__ __launch_bounds__(256, 8) void seg_partial_kernel(
    const float* __restrict__ rec, const float* __restrict__ aln,
    const int* __restrict__ mask,
    float* __restrict__ segsum, float* __restrict__ segcnt)
{
    __shared__ float binS[NCLS];
    __shared__ float binC[NCLS];
    const int tid = threadIdx.x;
    if (tid < NCLS) { binS[tid] = 0.0f; binC[tid] = 0.0f; }
    __syncthreads();

    const int b   = blockIdx.y;
    const int hw0 = blockIdx.x * PIX_PER_BLOCK + tid * 4;
    const int c0  = blockIdx.z * CH;

    const size_t base = (size_t)(b * Cd + c0) * HWd + hw0;
    const f4* __restrict__ rv = (const f4*)(rec + base);
    const f4* __restrict__ av = (const f4*)(aln + base);
    constexpr int CSTRIDE = HWd / 4;   // f4 stride between channels

    // independent mask load (L2-resident, shared by all c-chunks)
    const int4 m = *(const int4*)(mask + b * HWd + hw0);

    float accx = 0.f, accy = 0.f, accz = 0.f, accw = 0.f;

    // two 4-channel batches; each issues 8 nontemporal dwordx4 loads
    // (32 data VGPRs) before any use. Fits the 64-VGPR budget of (256,8)
    // without spilling (round-3: WRITE_SIZE 99KB at 36 VGPR pairwise).
#pragma unroll
    for (int batch = 0; batch < 2; ++batch) {
        const f4* r4 = rv + (size_t)(batch * 4) * CSTRIDE;
        const f4* a4 = av + (size_t)(batch * 4) * CSTRIDE;
        f4 R[4], A[4];
#pragma unroll
        for (int j = 0; j < 4; ++j) R[j] = __builtin_nontemporal_load(r4 + (size_t)j * CSTRIDE);
#pragma unroll
        for (int j = 0; j < 4; ++j) A[j] = __builtin_nontemporal_load(a4 + (size_t)j * CSTRIDE);
#pragma unroll
        for (int j = 0; j < 4; ++j) {
            float d;
            d = R[j].x - A[j].x; accx += d * d;
            d = R[j].y - A[j].y; accy += d * d;
            d = R[j].z - A[j].z; accz += d * d;
            d = R[j].w - A[j].w; accw += d * d;
        }
    }

    const float scale = 1.0f / (float)Cd;   // channel mean
    atomicAdd(&binS[m.x], accx * scale);    // LDS atomics (5 addrs, per-block)
    atomicAdd(&binS[m.y], accy * scale);
    atomicAdd(&binS[m.z], accz * scale);
    atomicAdd(&binS[m.w], accw * scale);
    if (blockIdx.z == 0) {
        atomicAdd(&binC[m.x], 1.0f);
        atomicAdd(&binC[m.y], 1.0f);
        atomicAdd(&binC[m.z], 1.0f);
        atomicAdd(&binC[m.w], 1.0f);
    }
    __syncthreads();
    // global atomics into the 80 final bins (measured faster than the
    // contention-free partials table in round 2)
    if (tid < NCLS) {
        atomicAdd(&segsum[b * NCLS + tid], binS[tid]);
        if (blockIdx.z == 0) atomicAdd(&segcnt[b * NCLS + tid], binC[tid]);
    }
}

// Kernel 2: 80 segments -> scalar. One block of 128 threads.
__global__ __launch_bounds__(128) void finalize_kernel(
    const float* __restrict__ segsum, const float* __restrict__ segcnt,
    float* __restrict__ out)
{
    __shared__ float sMax[128];
    __shared__ float sSum[128];
    const int t = threadIdx.x;

    float s = 0.0f, cnt = 0.0f;
    if (t < Bd * NCLS) { s = segsum[t]; cnt = segcnt[t]; }
    const float avg = s / fmaxf(cnt, 1.0f);   // empty segments -> 0

    sMax[t] = avg;
    __syncthreads();
#pragma unroll
    for (int off = 64; off > 0; off >>= 1) {
        if (t < off) sMax[t] = fmaxf(sMax[t], sMax[t + off]);
        __syncthreads();
    }
    const float wmax = sMax[0];

    float w = (wmax > 0.0f) ? (avg / (wmax + EPS2)) : (avg + EPS2);
    w = fminf(fmaxf(w, 0.0f), 1.0f);

    sSum[t] = s * (w * BETA + 1.0f);
    __syncthreads();
#pragma unroll
    for (int off = 64; off > 0; off >>= 1) {
        if (t < off) sSum[t] += sSum[t + off];
        __syncthreads();
    }
    if (t == 0) out[0] = sSum[0] / (float)(Bd * HWd);
}

extern "C" void kernel_launch(void* const* d_in, const int* in_sizes, int n_in,
                              void* d_out, int out_size, void* d_ws, size_t ws_size,
                              hipStream_t stream) {
    const float* rec  = (const float*)d_in[0];
    const float* aln  = (const float*)d_in[1];
    const int*   mask = (const int*)d_in[2];
    float* out = (float*)d_out;

    float* segsum = (float*)d_ws;
    float* segcnt = segsum + Bd * NCLS;

    // zero the 2*80 accumulators (ws is re-poisoned to 0xAA before every launch)
    (void)hipMemsetAsync(d_ws, 0, 2 * Bd * NCLS * sizeof(float), stream);

    dim3 grid(HWd / PIX_PER_BLOCK, Bd, NCCHUNK);   // (4, 16, 64) = 4096 blocks
    seg_partial_kernel<<<grid, 256, 0, stream>>>(rec, aln, mask, segsum, segcnt);
    finalize_kernel<<<1, 128, 0, stream>>>(segsum, segcnt, out);
}